// Round 1
// baseline (451.732 us; speedup 1.0000x reference)
//
#include <hip/hip_runtime.h>

#define N_NODES_C 100000
#define N_EDGES_C 1600000
#define IN_F 64
#define OUT_F 64
#define NK 4
#define DIM_C 3

// h layout: [node][out_feat][k]  -> edge kernel reads one float4 per lane.
// proj thread t (0..255): o = t>>2, k = t&3. Computes h[n][o][k] = dot(feat[n], W[k*64+o]).
__global__ __launch_bounds__(256) void proj_kernel(
    const float* __restrict__ feat, const float* __restrict__ W,
    const float* __restrict__ bias, float* __restrict__ h,
    float* __restrict__ out, int n_nodes)
{
    __shared__ float frow[IN_F];
    const int t = threadIdx.x;
    const int o = t >> 2;
    const int k = t & 3;
    // W row (k*64+o) into registers: 64 floats
    float wreg[IN_F];
    {
        const float4* W4 = reinterpret_cast<const float4*>(W + (size_t)(k * OUT_F + o) * IN_F);
        #pragma unroll
        for (int i = 0; i < IN_F / 4; ++i) {
            float4 v = W4[i];
            wreg[4*i+0] = v.x; wreg[4*i+1] = v.y; wreg[4*i+2] = v.z; wreg[4*i+3] = v.w;
        }
    }
    const float b = (t < OUT_F) ? bias[t] : 0.f;

    for (int n = blockIdx.x; n < n_nodes; n += gridDim.x) {
        if (t < IN_F / 4) {
            float4 v = reinterpret_cast<const float4*>(feat + (size_t)n * IN_F)[t];
            frow[4*t+0] = v.x; frow[4*t+1] = v.y; frow[4*t+2] = v.z; frow[4*t+3] = v.w;
        }
        __syncthreads();
        float acc = 0.f;
        #pragma unroll
        for (int i = 0; i < IN_F; ++i) acc = fmaf(frow[i], wreg[i], acc);
        h[(size_t)n * 256 + t] = acc;   // == h[n][o][k] since t = o*4+k
        if (t < OUT_F) out[(size_t)n * OUT_F + t] = frow[t] + b;  // residual + bias init
        __syncthreads();
    }
}

// One wave (64 lanes) per edge. lane = output feature.
__global__ __launch_bounds__(256) void edge_kernel(
    const float* __restrict__ pseudo, const int* __restrict__ src,
    const int* __restrict__ dst, const float* __restrict__ mu,
    const float* __restrict__ inv_sigma, const float* __restrict__ h,
    float* __restrict__ out, int n_edges)
{
    const int lane = threadIdx.x & 63;
    const int e = blockIdx.x * 4 + (threadIdx.x >> 6);
    if (e >= n_edges) return;

    const int s = src[e];
    const int d = dst[e];
    const float p0 = pseudo[(size_t)e * 3 + 0];
    const float p1 = pseudo[(size_t)e * 3 + 1];
    const float p2 = pseudo[(size_t)e * 3 + 2];

    float g[NK];
    #pragma unroll
    for (int k = 0; k < NK; ++k) {
        float d0 = p0 - mu[k*3+0], d1 = p1 - mu[k*3+1], d2 = p2 - mu[k*3+2];
        float s0 = inv_sigma[k*3+0], s1 = inv_sigma[k*3+1], s2 = inv_sigma[k*3+2];
        float ex = -0.5f * (d0*d0*s0*s0 + d1*d1*s1*s1 + d2*d2*s2*s2);
        g[k] = __expf(ex);
    }

    const float4 hv = *reinterpret_cast<const float4*>(h + ((size_t)s * OUT_F + lane) * 4);
    const float val = g[0]*hv.x + g[1]*hv.y + g[2]*hv.z + g[3]*hv.w;
    atomicAdd(&out[(size_t)d * OUT_F + lane], val);
}

extern "C" void kernel_launch(void* const* d_in, const int* in_sizes, int n_in,
                              void* d_out, int out_size, void* d_ws, size_t ws_size,
                              hipStream_t stream) {
    const float* feat      = (const float*)d_in[0];
    const float* pseudo    = (const float*)d_in[1];
    const int*   src       = (const int*)d_in[2];
    const int*   dst       = (const int*)d_in[3];
    const float* W_fc      = (const float*)d_in[4];
    const float* mu        = (const float*)d_in[5];
    const float* inv_sigma = (const float*)d_in[6];
    const float* bias      = (const float*)d_in[7];
    float* out = (float*)d_out;

    float* h = (float*)d_ws;  // 100000*256*4 = 102.4 MB

    // Projection + residual/bias init of out
    proj_kernel<<<2048, 256, 0, stream>>>(feat, W_fc, bias, h, out, N_NODES_C);

    // Edge aggregation (atomic scatter-add)
    const int edge_blocks = (N_EDGES_C + 3) / 4;
    edge_kernel<<<edge_blocks, 256, 0, stream>>>(pseudo, src, dst, mu, inv_sigma,
                                                 h, out, N_EDGES_C);
}

// Round 2
// 438.154 us; speedup vs baseline: 1.0310x; 1.0310x over previous
//
#include <hip/hip_runtime.h>

#define N_NODES_C 100000
#define N_EDGES_C 1600000
#define IN_F 64
#define OUT_F 64
#define NK 4

// ---------------------------------------------------------------------------
// proj: h[n][o][k] in bf16 (RNE). thread t: o = t>>2, k = t&3.
// Also initializes out = feat + bias (residual).
// ---------------------------------------------------------------------------
__global__ __launch_bounds__(256) void proj_kernel(
    const float* __restrict__ feat, const float* __restrict__ W,
    const float* __restrict__ bias, unsigned short* __restrict__ hb,
    float* __restrict__ out, int n_nodes)
{
    __shared__ float frow[IN_F];
    const int t = threadIdx.x;
    const int o = t >> 2;
    const int k = t & 3;
    float wreg[IN_F];
    {
        const float4* W4 = reinterpret_cast<const float4*>(W + (size_t)(k * OUT_F + o) * IN_F);
        #pragma unroll
        for (int i = 0; i < IN_F / 4; ++i) {
            float4 v = W4[i];
            wreg[4*i+0] = v.x; wreg[4*i+1] = v.y; wreg[4*i+2] = v.z; wreg[4*i+3] = v.w;
        }
    }
    const float b = (t < OUT_F) ? bias[t] : 0.f;

    for (int n = blockIdx.x; n < n_nodes; n += gridDim.x) {
        if (t < IN_F / 4) {
            float4 v = reinterpret_cast<const float4*>(feat + (size_t)n * IN_F)[t];
            frow[4*t+0] = v.x; frow[4*t+1] = v.y; frow[4*t+2] = v.z; frow[4*t+3] = v.w;
        }
        __syncthreads();
        float acc = 0.f;
        #pragma unroll
        for (int i = 0; i < IN_F; ++i) acc = fmaf(frow[i], wreg[i], acc);
        // bf16 RNE
        unsigned int u = __float_as_uint(acc);
        unsigned int r = (u + 0x7fffu + ((u >> 16) & 1u)) >> 16;
        hb[(size_t)n * 256 + t] = (unsigned short)r;
        if (t < OUT_F) out[(size_t)n * OUT_F + t] = frow[t] + b;
        __syncthreads();
    }
}

// ---------------------------------------------------------------------------
// gauss: one thread per edge, computes g[e][0..3], writes float4.
// ---------------------------------------------------------------------------
__global__ __launch_bounds__(256) void gauss_kernel(
    const float* __restrict__ pseudo, const float* __restrict__ mu,
    const float* __restrict__ inv_sigma, float* __restrict__ gbuf, int n_edges)
{
    const int e = blockIdx.x * 256 + threadIdx.x;
    if (e >= n_edges) return;
    const float p0 = pseudo[(size_t)e * 3 + 0];
    const float p1 = pseudo[(size_t)e * 3 + 1];
    const float p2 = pseudo[(size_t)e * 3 + 2];
    float4 g;
    float* gp = &g.x;
    #pragma unroll
    for (int k = 0; k < NK; ++k) {
        const float d0 = p0 - mu[k*3+0], d1 = p1 - mu[k*3+1], d2 = p2 - mu[k*3+2];
        const float s0 = inv_sigma[k*3+0], s1 = inv_sigma[k*3+1], s2 = inv_sigma[k*3+2];
        const float ex = -0.5f * (d0*d0*s0*s0 + d1*d1*s1*s1 + d2*d2*s2*s2);
        gp[k] = __expf(ex);
    }
    *reinterpret_cast<float4*>(gbuf + (size_t)e * 4) = g;
}

// ---------------------------------------------------------------------------
// edge: one wave per edge (grid-stride). lane = output feature.
// per lane: 8B bf16x4 h load, float4 g broadcast, 4-term dot, 1 atomicAdd.
// ---------------------------------------------------------------------------
__global__ __launch_bounds__(256) void edge_kernel(
    const int* __restrict__ src, const int* __restrict__ dst,
    const float* __restrict__ gbuf, const unsigned short* __restrict__ hb,
    float* __restrict__ out, int n_edges)
{
    const int lane = threadIdx.x & 63;
    const int w = (blockIdx.x * blockDim.x + threadIdx.x) >> 6;
    const int nw = (gridDim.x * blockDim.x) >> 6;
    for (int e = w; e < n_edges; e += nw) {
        const int s = src[e];
        const int d = dst[e];
        const float4 g = *reinterpret_cast<const float4*>(gbuf + (size_t)e * 4);
        const uint2 hv = *reinterpret_cast<const uint2*>(hb + (size_t)s * 256 + lane * 4);
        const float h0 = __uint_as_float(hv.x << 16);
        const float h1 = __uint_as_float(hv.x & 0xffff0000u);
        const float h2 = __uint_as_float(hv.y << 16);
        const float h3 = __uint_as_float(hv.y & 0xffff0000u);
        const float val = g.x*h0 + g.y*h1 + g.z*h2 + g.w*h3;
        atomicAdd(&out[(size_t)d * OUT_F + lane], val);
    }
}

extern "C" void kernel_launch(void* const* d_in, const int* in_sizes, int n_in,
                              void* d_out, int out_size, void* d_ws, size_t ws_size,
                              hipStream_t stream) {
    const float* feat      = (const float*)d_in[0];
    const float* pseudo    = (const float*)d_in[1];
    const int*   src       = (const int*)d_in[2];
    const int*   dst       = (const int*)d_in[3];
    const float* W_fc      = (const float*)d_in[4];
    const float* mu        = (const float*)d_in[5];
    const float* inv_sigma = (const float*)d_in[6];
    const float* bias      = (const float*)d_in[7];
    float* out = (float*)d_out;

    unsigned short* hb = (unsigned short*)d_ws;                    // 51.2 MB
    float* gbuf = (float*)((char*)d_ws + (size_t)N_NODES_C * 256 * 2); // 25.6 MB

    gauss_kernel<<<(N_EDGES_C + 255) / 256, 256, 0, stream>>>(
        pseudo, mu, inv_sigma, gbuf, N_EDGES_C);
    proj_kernel<<<2048, 256, 0, stream>>>(feat, W_fc, bias, hb, out, N_NODES_C);
    edge_kernel<<<4096, 256, 0, stream>>>(src, dst, gbuf, hb, out, N_EDGES_C);
}